// Round 12
// baseline (303.632 us; speedup 1.0000x reference)
//
#include <hip/hip_runtime.h>

#define D 128
#define EDGE_CAP 1024
typedef unsigned int uint32;
typedef __bf16 bf16x8 __attribute__((ext_vector_type(8)));
typedef float f32x4 __attribute__((ext_vector_type(4)));

__device__ __forceinline__ unsigned short f2bf(float f) {
    unsigned u = __float_as_uint(f);
    unsigned r = u + 0x7FFFu + ((u >> 16) & 1u);   // round-to-nearest-even
    return (unsigned short)(r >> 16);
}
__device__ __forceinline__ float bflo(uint32 u) { return __uint_as_float(u << 16); }
__device__ __forceinline__ float bfhi(uint32 u) { return __uint_as_float(u & 0xFFFF0000u); }

__device__ __forceinline__ void fma8(float* acc, uint4 r, float v) {
    acc[0] += v * bflo(r.x); acc[1] += v * bfhi(r.x);
    acc[2] += v * bflo(r.y); acc[3] += v * bfhi(r.y);
    acc[4] += v * bflo(r.z); acc[5] += v * bfhi(r.z);
    acc[6] += v * bflo(r.w); acc[7] += v * bfhi(r.w);
}

// ---------------------------------------------------------------------------
// Fused prep: x->bf16 | CSR row_ptr | W transpose+convert
// ---------------------------------------------------------------------------
__global__ __launch_bounds__(256) void prep_kernel(
    const float* __restrict__ x, unsigned short* __restrict__ xh, int n8,
    const int* __restrict__ row, int* __restrict__ row_ptr,
    int n_nodes, int n_edges,
    const float* __restrict__ Wl, const float* __restrict__ Wr,
    unsigned short* __restrict__ Wlt, unsigned short* __restrict__ Wrt,
    int nbConv, int nbRp) {
    const int b = blockIdx.x;
    if (b < nbConv) {
        const int id = b * 256 + threadIdx.x;
        if (id < n8) {
            const float4* p = (const float4*)x + (size_t)id * 2;
            float4 a = p[0], bb = p[1];
            uint4 o;
            o.x = f2bf(a.x) | ((uint32)f2bf(a.y) << 16);
            o.y = f2bf(a.z) | ((uint32)f2bf(a.w) << 16);
            o.z = f2bf(bb.x) | ((uint32)f2bf(bb.y) << 16);
            o.w = f2bf(bb.z) | ((uint32)f2bf(bb.w) << 16);
            ((uint4*)xh)[id] = o;
        }
    } else if (b < nbConv + nbRp) {
        const int e = (b - nbConv) * 256 + threadIdx.x;
        if (e < n_edges) {
            const int r = row[e];
            const int rp = (e == 0) ? -1 : row[e - 1];
            for (int n = rp + 1; n <= r; ++n) row_ptr[n] = e;
            if (e == n_edges - 1)
                for (int n = r + 1; n <= n_nodes; ++n) row_ptr[n] = n_edges;
        }
    } else {
        const int id = (b - nbConv - nbRp) * 256 + threadIdx.x;   // 0..16383
        if (id < 16384) {
            const int n = id & 127, k = id >> 7;
            Wlt[n * 128 + k] = f2bf(Wl[k * 128 + n]);
            Wrt[n * 128 + k] = f2bf(Wr[k * 128 + n]);
        }
    }
}

// ---------------------------------------------------------------------------
// FUSED SpMM+GEMM, barrier-free epilogue with ROW REPLICATION.
// Block = 256 thr = 4 waves = 16 nodes (round-5 gather, proven 59.8us:
// one node per 16-lane group, all 16 in parallel, quad-pipelined).
// Each wave's 4 finished rows -> per-wave LDS A_w[4][136] (pad: 2-way max).
// Epilogue per wave, NO __syncthreads: 64 MFMAs where A-row fr reads LDS
// row fr&3 (rows replicated 4x; C rows 4..15 are duplicates, discarded).
// x-half of K read from global (clamped), W from L2-hot Wlt/Wrt.
// ---------------------------------------------------------------------------
__global__ __launch_bounds__(256) void spmm_gemm_kernel(
    const unsigned short* __restrict__ xh,
    const int* __restrict__ row_ptr,
    const int* __restrict__ col,
    const float* __restrict__ val,
    const unsigned short* __restrict__ Wlt,
    const unsigned short* __restrict__ Wrt,
    const float* __restrict__ b_l,
    float* __restrict__ out, int n_nodes) {
    __shared__ int2 scv[EDGE_CAP];               // 8 KB
    __shared__ unsigned short A_w[4][4][136];    // 4.25 KB per-wave tiles
    const int tid = threadIdx.x;
    const int n0 = blockIdx.x * 16;
    const int e0 = row_ptr[n0];
    const int e1 = row_ptr[min(n0 + 16, n_nodes)];
    const int ne = e1 - e0;
    const bool fits = (ne <= EDGE_CAP);
    if (fits) {
        for (int t = tid; t < ne; t += 256)
            scv[t] = make_int2(col[e0 + t], __float_as_int(val[e0 + t]));
    }
    __syncthreads();

    const int wv = tid >> 6, lane = tid & 63;
    const int g = lane >> 4, lq = lane & 15;
    const int nw0 = n0 + wv * 4;          // wave's 4 nodes
    const int n = nw0 + g;                // this group's node

    int s = 0, e = 0;
    if (n < n_nodes) { s = row_ptr[n]; e = row_ptr[n + 1]; }

    float acc[8] = {0.f, 0.f, 0.f, 0.f, 0.f, 0.f, 0.f, 0.f};

    if (fits) {
        auto fetch = [&](int idx, int& c, float& v) {
            if (idx < e) {
                const int li = idx - e0;
                c = scv[li].x; v = __int_as_float(scv[li].y);
            } else { c = 0; v = 0.f; }
        };
        int i = s;
        int c0, c1, c2, c3; float v0, v1, v2, v3;
        fetch(i + 0, c0, v0); fetch(i + 1, c1, v1);
        fetch(i + 2, c2, v2); fetch(i + 3, c3, v3);
        uint4 r0 = *(const uint4*)&xh[c0 * D + lq * 8];
        uint4 r1 = *(const uint4*)&xh[c1 * D + lq * 8];
        uint4 r2 = *(const uint4*)&xh[c2 * D + lq * 8];
        uint4 r3 = *(const uint4*)&xh[c3 * D + lq * 8];
        while (i < e) {
            const int i2 = i + 4;
            int d0, d1, d2, d3; float w0, w1, w2, w3;
            fetch(i2 + 0, d0, w0); fetch(i2 + 1, d1, w1);
            fetch(i2 + 2, d2, w2); fetch(i2 + 3, d3, w3);
            const uint4 t0 = *(const uint4*)&xh[d0 * D + lq * 8];
            const uint4 t1 = *(const uint4*)&xh[d1 * D + lq * 8];
            const uint4 t2 = *(const uint4*)&xh[d2 * D + lq * 8];
            const uint4 t3 = *(const uint4*)&xh[d3 * D + lq * 8];
            fma8(acc, r0, v0);
            fma8(acc, r1, v1);
            fma8(acc, r2, v2);
            fma8(acc, r3, v3);
            r0 = t0; r1 = t1; r2 = t2; r3 = t3;
            v0 = w0; v1 = w1; v2 = w2; v3 = w3;
            i = i2;
        }
    } else {
        for (int j = s; j < e; ++j) {
            const int c = col[j];
            const float v = val[j];
            const uint4 r = *(const uint4*)&xh[(size_t)c * D + lq * 8];
            fma8(acc, r, v);
        }
    }

    // ---- pack out_l row -> per-wave LDS (group g owns row g) ----
    {
        uint4 o;
        o.x = f2bf(acc[0]) | ((uint32)f2bf(acc[1]) << 16);
        o.y = f2bf(acc[2]) | ((uint32)f2bf(acc[3]) << 16);
        o.z = f2bf(acc[4]) | ((uint32)f2bf(acc[5]) << 16);
        o.w = f2bf(acc[6]) | ((uint32)f2bf(acc[7]) << 16);
        *(uint4*)&A_w[wv][g][lq * 8] = o;
    }
    // wave-private LDS: compiler's lgkmcnt ordering suffices (no barrier)

    // ---- per-wave MFMA epilogue: C[4x128] (rows replicated to 16) ----
    const int fr = lane & 15, hh = lane >> 4;
    const int kofs = hh * 8;
    const int arow = fr & 3;
    const int xnode = min(nw0 + arow, n_nodes - 1);   // clamped global A row
    f32x4 acc2[8];
#pragma unroll
    for (int nt = 0; nt < 8; ++nt) acc2[nt] = (f32x4){0.f, 0.f, 0.f, 0.f};

#pragma unroll
    for (int st = 0; st < 4; ++st) {      // out_l @ W_l  (K 0..127)
        const int k0 = st * 32;
        const bf16x8 a = *(const bf16x8*)&A_w[wv][arow][k0 + kofs];
#pragma unroll
        for (int nt = 0; nt < 8; ++nt) {
            const bf16x8 b =
                *(const bf16x8*)&Wlt[(nt * 16 + fr) * 128 + k0 + kofs];
            acc2[nt] = __builtin_amdgcn_mfma_f32_16x16x32_bf16(
                a, b, acc2[nt], 0, 0, 0);
        }
    }
#pragma unroll
    for (int st = 0; st < 4; ++st) {      // x @ W_r  (K 128..255)
        const int k0 = st * 32;
        const bf16x8 a =
            *(const bf16x8*)&xh[(size_t)xnode * D + k0 + kofs];
#pragma unroll
        for (int nt = 0; nt < 8; ++nt) {
            const bf16x8 b =
                *(const bf16x8*)&Wrt[(nt * 16 + fr) * 128 + k0 + kofs];
            acc2[nt] = __builtin_amdgcn_mfma_f32_16x16x32_bf16(
                a, b, acc2[nt], 0, 0, 0);
        }
    }

    // ---- C write: valid rows are 0..3 (hh==0 lanes), col = nt*16+fr ----
    if (hh == 0) {
#pragma unroll
        for (int nt = 0; nt < 8; ++nt) {
            const int ncol = nt * 16 + fr;
            const float bias = b_l[ncol];
#pragma unroll
            for (int j = 0; j < 4; ++j) {
                const int m = nw0 + j;
                if (m < n_nodes)
                    out[(size_t)m * D + ncol] = acc2[nt][j] + bias;
            }
        }
    }
}

// ===========================================================================
// Fallback f32 path if ws is too small for bf16 staging.
// ===========================================================================
__global__ void build_rowptr_kernel(const int* __restrict__ row,
                                    int* __restrict__ row_ptr,
                                    int n_nodes, int n_edges) {
    int e = blockIdx.x * blockDim.x + threadIdx.x;
    if (e >= n_edges) return;
    int r = row[e];
    int rp = (e == 0) ? -1 : row[e - 1];
    for (int n = rp + 1; n <= r; ++n) row_ptr[n] = e;
    if (e == n_edges - 1)
        for (int n = r + 1; n <= n_nodes; ++n) row_ptr[n] = n_edges;
}

__global__ __launch_bounds__(128) void spmm_kernel(
    const float* __restrict__ x, const int* __restrict__ row_ptr,
    const int* __restrict__ col, const float* __restrict__ val,
    float* __restrict__ out_l) {
    const int n = blockIdx.x;
    const int d = threadIdx.x;
    const int start = row_ptr[n];
    const int end = row_ptr[n + 1];
    float acc = 0.0f;
    for (int e = start; e < end; ++e)
        acc += val[e] * x[(size_t)col[e] * D + d];
    out_l[(size_t)n * D + d] = acc;
}

__global__ __launch_bounds__(256) void fused_gemm_kernel(
    const float* __restrict__ xin, const float* __restrict__ W_l,
    const float* __restrict__ b_l, const float* __restrict__ W_r,
    float* __restrict__ out, int M) {
    __shared__ float As[64][68];
    __shared__ float Ws[64][132];
    const int tid = threadIdx.x;
    const int tx = tid & 15;
    const int ty = tid >> 4;
    const int ty4 = ty * 4;
    const int m0 = blockIdx.x * 64;
    float acc[4][8];
#pragma unroll
    for (int i = 0; i < 4; ++i)
#pragma unroll
        for (int j = 0; j < 8; ++j) acc[i][j] = 0.0f;
    for (int kt = 0; kt < 4; ++kt) {
        const float* Asrc = (kt < 2) ? out : xin;
        const float* Wsrc = (kt < 2) ? W_l : W_r;
        const int koff = (kt & 1) * 64;
        __syncthreads();
#pragma unroll
        for (int r = 0; r < 4; ++r) {
            const int idx = tid + r * 256;
            const int m = idx >> 4;
            const int kq = idx & 15;
            float4 a = make_float4(0.f, 0.f, 0.f, 0.f);
            if (m0 + m < M)
                a = *(const float4*)&Asrc[(size_t)(m0 + m) * D + koff + kq * 4];
            *(float4*)&As[m][kq * 4] = a;
        }
#pragma unroll
        for (int r = 0; r < 8; ++r) {
            const int idx = tid + r * 256;
            const int k = idx >> 5;
            const int j4 = idx & 31;
            *(float4*)&Ws[k][j4 * 4] =
                *(const float4*)&Wsrc[(size_t)(koff + k) * D + j4 * 4];
        }
        __syncthreads();
#pragma unroll 4
        for (int k = 0; k < 64; ++k) {
            const float a0 = As[ty4 + 0][k], a1 = As[ty4 + 1][k];
            const float a2 = As[ty4 + 2][k], a3 = As[ty4 + 3][k];
            const float4 w0 = *(const float4*)&Ws[k][tx * 4];
            const float4 w1 = *(const float4*)&Ws[k][64 + tx * 4];
            acc[0][0] += a0 * w0.x; acc[0][1] += a0 * w0.y; acc[0][2] += a0 * w0.z; acc[0][3] += a0 * w0.w;
            acc[0][4] += a0 * w1.x; acc[0][5] += a0 * w1.y; acc[0][6] += a0 * w1.z; acc[0][7] += a0 * w1.w;
            acc[1][0] += a1 * w0.x; acc[1][1] += a1 * w0.y; acc[1][2] += a1 * w0.z; acc[1][3] += a1 * w0.w;
            acc[1][4] += a1 * w1.x; acc[1][5] += a1 * w1.y; acc[1][6] += a1 * w1.z; acc[1][7] += a1 * w1.w;
            acc[2][0] += a2 * w0.x; acc[2][1] += a2 * w0.y; acc[2][2] += a2 * w0.z; acc[2][3] += a2 * w0.w;
            acc[2][4] += a2 * w1.x; acc[2][5] += a2 * w1.y; acc[2][6] += a2 * w1.z; acc[2][7] += a2 * w1.w;
            acc[3][0] += a3 * w0.x; acc[3][1] += a3 * w0.y; acc[3][2] += a3 * w0.z; acc[3][3] += a3 * w0.w;
            acc[3][4] += a3 * w1.x; acc[3][5] += a3 * w1.y; acc[3][6] += a3 * w1.z; acc[3][7] += a3 * w1.w;
        }
    }
    const float4 bv0 = *(const float4*)&b_l[tx * 4];
    const float4 bv1 = *(const float4*)&b_l[64 + tx * 4];
#pragma unroll
    for (int i = 0; i < 4; ++i) {
        const int m = m0 + ty4 + i;
        if (m < M) {
            float4 o0, o1;
            o0.x = acc[i][0] + bv0.x; o0.y = acc[i][1] + bv0.y;
            o0.z = acc[i][2] + bv0.z; o0.w = acc[i][3] + bv0.w;
            o1.x = acc[i][4] + bv1.x; o1.y = acc[i][5] + bv1.y;
            o1.z = acc[i][6] + bv1.z; o1.w = acc[i][7] + bv1.w;
            *(float4*)&out[(size_t)m * D + tx * 4] = o0;
            *(float4*)&out[(size_t)m * D + 64 + tx * 4] = o1;
        }
    }
}

static inline size_t align256(size_t x) { return (x + 255) & ~(size_t)255; }

extern "C" void kernel_launch(void* const* d_in, const int* in_sizes, int n_in,
                              void* d_out, int out_size, void* d_ws, size_t ws_size,
                              hipStream_t stream) {
    const float* x   = (const float*)d_in[0];
    const int*   row = (const int*)d_in[1];
    const int*   col = (const int*)d_in[2];
    const float* val = (const float*)d_in[3];
    const float* W_l = (const float*)d_in[4];
    const float* b_l = (const float*)d_in[5];
    const float* W_r = (const float*)d_in[6];
    float* out = (float*)d_out;

    const int n_nodes = in_sizes[0] / D;
    const int n_edges = in_sizes[1];

    const size_t xh_bytes = (size_t)n_nodes * D * 2;
    const size_t wt_bytes = (size_t)D * D * 2;
    const size_t rp_bytes = (size_t)(n_nodes + 1) * 4;
    size_t off = 0;
    const size_t xh_off  = off; off += align256(xh_bytes);
    const size_t wlt_off = off; off += align256(wt_bytes);
    const size_t wrt_off = off; off += align256(wt_bytes);
    const size_t rp_off  = off; off += align256(rp_bytes);
    const size_t needed  = off + 65536;

    if (ws_size >= needed) {
        unsigned short* xh  = (unsigned short*)((char*)d_ws + xh_off);
        unsigned short* Wlt = (unsigned short*)((char*)d_ws + wlt_off);
        unsigned short* Wrt = (unsigned short*)((char*)d_ws + wrt_off);
        int* row_ptr        = (int*)((char*)d_ws + rp_off);

        const int n8 = n_nodes * D / 8;
        const int nbConv = (n8 + 255) / 256;
        const int nbRp   = (n_edges + 255) / 256;
        const int nbW    = 64;
        prep_kernel<<<nbConv + nbRp + nbW, 256, 0, stream>>>(
            x, xh, n8, row, row_ptr, n_nodes, n_edges,
            W_l, W_r, Wlt, Wrt, nbConv, nbRp);
        spmm_gemm_kernel<<<(n_nodes + 15) / 16, 256, 0, stream>>>(
            xh, row_ptr, col, val, Wlt, Wrt, b_l, out, n_nodes);
    } else {
        int* row_ptr = (int*)d_ws;
        build_rowptr_kernel<<<(n_edges + 255) / 256, 256, 0, stream>>>(
            row, row_ptr, n_nodes, n_edges);
        spmm_kernel<<<n_nodes, 128, 0, stream>>>(x, row_ptr, col, val, out);
        fused_gemm_kernel<<<(n_nodes + 63) / 64, 256, 0, stream>>>(
            x, W_l, b_l, W_r, out, n_nodes);
    }
}

// Round 13
// 125.162 us; speedup vs baseline: 2.4259x; 2.4259x over previous
//
#include <hip/hip_runtime.h>

#define D 128
#define EDGE_CAP 1024
typedef unsigned int uint32;
typedef __bf16 bf16x8 __attribute__((ext_vector_type(8)));
typedef float f32x4 __attribute__((ext_vector_type(4)));

__device__ __forceinline__ unsigned short f2bf(float f) {
    unsigned u = __float_as_uint(f);
    unsigned r = u + 0x7FFFu + ((u >> 16) & 1u);   // round-to-nearest-even
    return (unsigned short)(r >> 16);
}
__device__ __forceinline__ float bflo(uint32 u) { return __uint_as_float(u << 16); }
__device__ __forceinline__ float bfhi(uint32 u) { return __uint_as_float(u & 0xFFFF0000u); }

__device__ __forceinline__ void fma8(float* acc, uint4 r, float v) {
    acc[0] += v * bflo(r.x); acc[1] += v * bfhi(r.x);
    acc[2] += v * bflo(r.y); acc[3] += v * bfhi(r.y);
    acc[4] += v * bflo(r.z); acc[5] += v * bfhi(r.z);
    acc[6] += v * bflo(r.w); acc[7] += v * bfhi(r.w);
}

// ---------------------------------------------------------------------------
// Fused prep: x->bf16 | CSR row_ptr | W transpose+convert
// ---------------------------------------------------------------------------
__global__ __launch_bounds__(256) void prep_kernel(
    const float* __restrict__ x, unsigned short* __restrict__ xh, int n8,
    const int* __restrict__ row, int* __restrict__ row_ptr,
    int n_nodes, int n_edges,
    const float* __restrict__ Wl, const float* __restrict__ Wr,
    unsigned short* __restrict__ Wlt, unsigned short* __restrict__ Wrt,
    int nbConv, int nbRp) {
    const int b = blockIdx.x;
    if (b < nbConv) {
        const int id = b * 256 + threadIdx.x;
        if (id < n8) {
            const float4* p = (const float4*)x + (size_t)id * 2;
            float4 a = p[0], bb = p[1];
            uint4 o;
            o.x = f2bf(a.x) | ((uint32)f2bf(a.y) << 16);
            o.y = f2bf(a.z) | ((uint32)f2bf(a.w) << 16);
            o.z = f2bf(bb.x) | ((uint32)f2bf(bb.y) << 16);
            o.w = f2bf(bb.z) | ((uint32)f2bf(bb.w) << 16);
            ((uint4*)xh)[id] = o;
        }
    } else if (b < nbConv + nbRp) {
        const int e = (b - nbConv) * 256 + threadIdx.x;
        if (e < n_edges) {
            const int r = row[e];
            const int rp = (e == 0) ? -1 : row[e - 1];
            for (int n = rp + 1; n <= r; ++n) row_ptr[n] = e;
            if (e == n_edges - 1)
                for (int n = r + 1; n <= n_nodes; ++n) row_ptr[n] = n_edges;
        }
    } else {
        const int id = (b - nbConv - nbRp) * 256 + threadIdx.x;   // 0..16383
        if (id < 16384) {
            const int n = id & 127, k = id >> 7;
            Wlt[n * 128 + k] = f2bf(Wl[k * 128 + n]);
            Wrt[n * 128 + k] = f2bf(Wr[k * 128 + n]);
        }
    }
}

// ---------------------------------------------------------------------------
// FUSED SpMM+GEMM, round-10 structure + XOR-swizzled A-tile + two tiles per
// block software-pipelined:
//   stage(T0); B; gather(T0); B; {stage(T1) || epilogue(T0)}; B;
//   gather(T1); B; epilogue(T1)
// Tile = 16 nodes, one 16-lane group per node (full parallel gather, the
// proven round-5 quad pipeline). A-tile [16][256] bf16 (out_l | x), 16B
// chunks XOR-swizzled by row&7 -> 2-way max on MFMA fragment reads.
// Epilogue: wave wv owns output cols [wv*32, wv*32+32): 16 MFMAs.
// ---------------------------------------------------------------------------
__global__ __launch_bounds__(256) void spmm_gemm_kernel(
    const unsigned short* __restrict__ xh,
    const int* __restrict__ row_ptr,
    const int* __restrict__ col,
    const float* __restrict__ val,
    const unsigned short* __restrict__ Wlt,
    const unsigned short* __restrict__ Wrt,
    const float* __restrict__ b_l,
    float* __restrict__ out, int n_nodes) {
    __shared__ int2 scv[EDGE_CAP];               // 8 KB (re-staged per tile)
    __shared__ unsigned short A[2][16][256];     // 16 KB, swizzled chunks
    const int tid = threadIdx.x;
    const int wv = tid >> 6, lane = tid & 63;
    const int g = lane >> 4, lq = lane & 15;

    const int n0a = blockIdx.x * 32;
    const int n0b = n0a + 16;
    const bool haveB = (n0b < n_nodes);

    int e0a = 0, e0b = 0;
    bool fita = false, fitb = false;

    // ---- stage scv + x-half for a tile ----
    auto stage_scv = [&](int n0, int& e0, bool& fits) {
        e0 = row_ptr[n0];
        const int e1 = row_ptr[min(n0 + 16, n_nodes)];
        const int ne = e1 - e0;
        fits = (ne <= EDGE_CAP);
        if (fits) {
            for (int t = tid; t < ne; t += 256)
                scv[t] = make_int2(col[e0 + t], __float_as_int(val[e0 + t]));
        }
    };
    auto stage_x = [&](int buf, int n0) {
        const int r = tid >> 4, c = tid & 15;
        uint4 v = make_uint4(0u, 0u, 0u, 0u);
        if (n0 + r < n_nodes)
            v = *(const uint4*)&xh[(size_t)(n0 + r) * D + c * 8];
        *(uint4*)&A[buf][r][128 + ((c ^ (r & 7)) * 8)] = v;
    };

    // ---- gather one tile (group-per-node, quad pipeline) ----
    auto gather = [&](int buf, int n0, int e0, bool fits) {
        const int nloc = wv * 4 + g;
        const int n = n0 + nloc;
        int s = 0, e = 0;
        if (n < n_nodes) { s = row_ptr[n]; e = row_ptr[n + 1]; }
        float acc[8] = {0.f, 0.f, 0.f, 0.f, 0.f, 0.f, 0.f, 0.f};

        if (fits) {
            auto fetch = [&](int idx, int& c, float& v) {
                if (idx < e) {
                    const int li = idx - e0;
                    c = scv[li].x; v = __int_as_float(scv[li].y);
                } else { c = 0; v = 0.f; }
            };
            int i = s;
            int c0, c1, c2, c3; float v0, v1, v2, v3;
            fetch(i + 0, c0, v0); fetch(i + 1, c1, v1);
            fetch(i + 2, c2, v2); fetch(i + 3, c3, v3);
            uint4 r0 = *(const uint4*)&xh[c0 * D + lq * 8];
            uint4 r1 = *(const uint4*)&xh[c1 * D + lq * 8];
            uint4 r2 = *(const uint4*)&xh[c2 * D + lq * 8];
            uint4 r3 = *(const uint4*)&xh[c3 * D + lq * 8];
            while (i < e) {
                const int i2 = i + 4;
                int d0, d1, d2, d3; float w0, w1, w2, w3;
                fetch(i2 + 0, d0, w0); fetch(i2 + 1, d1, w1);
                fetch(i2 + 2, d2, w2); fetch(i2 + 3, d3, w3);
                const uint4 t0 = *(const uint4*)&xh[d0 * D + lq * 8];
                const uint4 t1 = *(const uint4*)&xh[d1 * D + lq * 8];
                const uint4 t2 = *(const uint4*)&xh[d2 * D + lq * 8];
                const uint4 t3 = *(const uint4*)&xh[d3 * D + lq * 8];
                fma8(acc, r0, v0);
                fma8(acc, r1, v1);
                fma8(acc, r2, v2);
                fma8(acc, r3, v3);
                r0 = t0; r1 = t1; r2 = t2; r3 = t3;
                v0 = w0; v1 = w1; v2 = w2; v3 = w3;
                i = i2;
            }
        } else {
            for (int j = s; j < e; ++j) {
                const int c = col[j];
                const float v = val[j];
                const uint4 r = *(const uint4*)&xh[(size_t)c * D + lq * 8];
                fma8(acc, r, v);
            }
        }

        uint4 o;
        o.x = f2bf(acc[0]) | ((uint32)f2bf(acc[1]) << 16);
        o.y = f2bf(acc[2]) | ((uint32)f2bf(acc[3]) << 16);
        o.z = f2bf(acc[4]) | ((uint32)f2bf(acc[5]) << 16);
        o.w = f2bf(acc[6]) | ((uint32)f2bf(acc[7]) << 16);
        *(uint4*)&A[buf][nloc][(lq ^ (nloc & 7)) * 8] = o;
    };

    // ---- epilogue: wave wv -> output cols [wv*32, +32) of the tile ----
    auto epilogue = [&](int buf, int n0) {
        const int fr = lane & 15, hh = lane >> 4;
        const int kofs = hh * 8;
        f32x4 acc2[2];
        acc2[0] = (f32x4){0.f, 0.f, 0.f, 0.f};
        acc2[1] = (f32x4){0.f, 0.f, 0.f, 0.f};
#pragma unroll
        for (int st = 0; st < 8; ++st) {
            const int h = st >> 2;                     // 0: out_l/Wl, 1: x/Wr
            const int cc = (st & 3) * 4 + hh;          // 16B chunk in half
            const bf16x8 a =
                *(const bf16x8*)&A[buf][fr][h * 128 + ((cc ^ (fr & 7)) * 8)];
            const unsigned short* Wsel = h ? Wrt : Wlt;
            const int kk = (st & 3) * 32 + kofs;
#pragma unroll
            for (int nr = 0; nr < 2; ++nr) {
                const int ncol = wv * 32 + nr * 16 + fr;
                const bf16x8 b = *(const bf16x8*)&Wsel[ncol * 128 + kk];
                acc2[nr] = __builtin_amdgcn_mfma_f32_16x16x32_bf16(
                    a, b, acc2[nr], 0, 0, 0);
            }
        }
        const int r0c = hh * 4;
#pragma unroll
        for (int nr = 0; nr < 2; ++nr) {
            const int ncol = wv * 32 + nr * 16 + fr;
            const float bias = b_l[ncol];
#pragma unroll
            for (int j = 0; j < 4; ++j) {
                const int m = n0 + r0c + j;
                if (m < n_nodes)
                    out[(size_t)m * D + ncol] = acc2[nr][j] + bias;
            }
        }
    };

    // ---- pipeline ----
    stage_scv(n0a, e0a, fita);
    stage_x(0, n0a);
    __syncthreads();
    gather(0, n0a, e0a, fita);
    __syncthreads();
    if (haveB) { stage_scv(n0b, e0b, fitb); stage_x(1, n0b); }
    epilogue(0, n0a);
    __syncthreads();
    if (haveB) {
        gather(1, n0b, e0b, fitb);
        __syncthreads();
        epilogue(1, n0b);
    }
}

// ===========================================================================
// Fallback f32 path if ws is too small for bf16 staging.
// ===========================================================================
__global__ void build_rowptr_kernel(const int* __restrict__ row,
                                    int* __restrict__ row_ptr,
                                    int n_nodes, int n_edges) {
    int e = blockIdx.x * blockDim.x + threadIdx.x;
    if (e >= n_edges) return;
    int r = row[e];
    int rp = (e == 0) ? -1 : row[e - 1];
    for (int n = rp + 1; n <= r; ++n) row_ptr[n] = e;
    if (e == n_edges - 1)
        for (int n = r + 1; n <= n_nodes; ++n) row_ptr[n] = n_edges;
}

__global__ __launch_bounds__(128) void spmm_kernel(
    const float* __restrict__ x, const int* __restrict__ row_ptr,
    const int* __restrict__ col, const float* __restrict__ val,
    float* __restrict__ out_l) {
    const int n = blockIdx.x;
    const int d = threadIdx.x;
    const int start = row_ptr[n];
    const int end = row_ptr[n + 1];
    float acc = 0.0f;
    for (int e = start; e < end; ++e)
        acc += val[e] * x[(size_t)col[e] * D + d];
    out_l[(size_t)n * D + d] = acc;
}

__global__ __launch_bounds__(256) void fused_gemm_kernel(
    const float* __restrict__ xin, const float* __restrict__ W_l,
    const float* __restrict__ b_l, const float* __restrict__ W_r,
    float* __restrict__ out, int M) {
    __shared__ float As[64][68];
    __shared__ float Ws[64][132];
    const int tid = threadIdx.x;
    const int tx = tid & 15;
    const int ty = tid >> 4;
    const int ty4 = ty * 4;
    const int m0 = blockIdx.x * 64;
    float acc[4][8];
#pragma unroll
    for (int i = 0; i < 4; ++i)
#pragma unroll
        for (int j = 0; j < 8; ++j) acc[i][j] = 0.0f;
    for (int kt = 0; kt < 4; ++kt) {
        const float* Asrc = (kt < 2) ? out : xin;
        const float* Wsrc = (kt < 2) ? W_l : W_r;
        const int koff = (kt & 1) * 64;
        __syncthreads();
#pragma unroll
        for (int r = 0; r < 4; ++r) {
            const int idx = tid + r * 256;
            const int m = idx >> 4;
            const int kq = idx & 15;
            float4 a = make_float4(0.f, 0.f, 0.f, 0.f);
            if (m0 + m < M)
                a = *(const float4*)&Asrc[(size_t)(m0 + m) * D + koff + kq * 4];
            *(float4*)&As[m][kq * 4] = a;
        }
#pragma unroll
        for (int r = 0; r < 8; ++r) {
            const int idx = tid + r * 256;
            const int k = idx >> 5;
            const int j4 = idx & 31;
            *(float4*)&Ws[k][j4 * 4] =
                *(const float4*)&Wsrc[(size_t)(koff + k) * D + j4 * 4];
        }
        __syncthreads();
#pragma unroll 4
        for (int k = 0; k < 64; ++k) {
            const float a0 = As[ty4 + 0][k], a1 = As[ty4 + 1][k];
            const float a2 = As[ty4 + 2][k], a3 = As[ty4 + 3][k];
            const float4 w0 = *(const float4*)&Ws[k][tx * 4];
            const float4 w1 = *(const float4*)&Ws[k][64 + tx * 4];
            acc[0][0] += a0 * w0.x; acc[0][1] += a0 * w0.y; acc[0][2] += a0 * w0.z; acc[0][3] += a0 * w0.w;
            acc[0][4] += a0 * w1.x; acc[0][5] += a0 * w1.y; acc[0][6] += a0 * w1.z; acc[0][7] += a0 * w1.w;
            acc[1][0] += a1 * w0.x; acc[1][1] += a1 * w0.y; acc[1][2] += a1 * w0.z; acc[1][3] += a1 * w0.w;
            acc[1][4] += a1 * w1.x; acc[1][5] += a1 * w1.y; acc[1][6] += a1 * w1.z; acc[1][7] += a1 * w1.w;
            acc[2][0] += a2 * w0.x; acc[2][1] += a2 * w0.y; acc[2][2] += a2 * w0.z; acc[2][3] += a2 * w0.w;
            acc[2][4] += a2 * w1.x; acc[2][5] += a2 * w1.y; acc[2][6] += a2 * w1.z; acc[2][7] += a2 * w1.w;
            acc[3][0] += a3 * w0.x; acc[3][1] += a3 * w0.y; acc[3][2] += a3 * w0.z; acc[3][3] += a3 * w0.w;
            acc[3][4] += a3 * w1.x; acc[3][5] += a3 * w1.y; acc[3][6] += a3 * w1.z; acc[3][7] += a3 * w1.w;
        }
    }
    const float4 bv0 = *(const float4*)&b_l[tx * 4];
    const float4 bv1 = *(const float4*)&b_l[64 + tx * 4];
#pragma unroll
    for (int i = 0; i < 4; ++i) {
        const int m = m0 + ty4 + i;
        if (m < M) {
            float4 o0, o1;
            o0.x = acc[i][0] + bv0.x; o0.y = acc[i][1] + bv0.y;
            o0.z = acc[i][2] + bv0.z; o0.w = acc[i][3] + bv0.w;
            o1.x = acc[i][4] + bv1.x; o1.y = acc[i][5] + bv1.y;
            o1.z = acc[i][6] + bv1.z; o1.w = acc[i][7] + bv1.w;
            *(float4*)&out[(size_t)m * D + tx * 4] = o0;
            *(float4*)&out[(size_t)m * D + 64 + tx * 4] = o1;
        }
    }
}

static inline size_t align256(size_t x) { return (x + 255) & ~(size_t)255; }

extern "C" void kernel_launch(void* const* d_in, const int* in_sizes, int n_in,
                              void* d_out, int out_size, void* d_ws, size_t ws_size,
                              hipStream_t stream) {
    const float* x   = (const float*)d_in[0];
    const int*   row = (const int*)d_in[1];
    const int*   col = (const int*)d_in[2];
    const float* val = (const float*)d_in[3];
    const float* W_l = (const float*)d_in[4];
    const float* b_l = (const float*)d_in[5];
    const float* W_r = (const float*)d_in[6];
    float* out = (float*)d_out;

    const int n_nodes = in_sizes[0] / D;
    const int n_edges = in_sizes[1];

    const size_t xh_bytes = (size_t)n_nodes * D * 2;
    const size_t wt_bytes = (size_t)D * D * 2;
    const size_t rp_bytes = (size_t)(n_nodes + 1) * 4;
    size_t off = 0;
    const size_t xh_off  = off; off += align256(xh_bytes);
    const size_t wlt_off = off; off += align256(wt_bytes);
    const size_t wrt_off = off; off += align256(wt_bytes);
    const size_t rp_off  = off; off += align256(rp_bytes);
    const size_t needed  = off + 65536;

    if (ws_size >= needed) {
        unsigned short* xh  = (unsigned short*)((char*)d_ws + xh_off);
        unsigned short* Wlt = (unsigned short*)((char*)d_ws + wlt_off);
        unsigned short* Wrt = (unsigned short*)((char*)d_ws + wrt_off);
        int* row_ptr        = (int*)((char*)d_ws + rp_off);

        const int n8 = n_nodes * D / 8;
        const int nbConv = (n8 + 255) / 256;
        const int nbRp   = (n_edges + 255) / 256;
        const int nbW    = 64;
        prep_kernel<<<nbConv + nbRp + nbW, 256, 0, stream>>>(
            x, xh, n8, row, row_ptr, n_nodes, n_edges,
            W_l, W_r, Wlt, Wrt, nbConv, nbRp);
        spmm_gemm_kernel<<<(n_nodes + 31) / 32, 256, 0, stream>>>(
            xh, row_ptr, col, val, Wlt, Wrt, b_l, out, n_nodes);
    } else {
        int* row_ptr = (int*)d_ws;
        build_rowptr_kernel<<<(n_edges + 255) / 256, 256, 0, stream>>>(
            row, row_ptr, n_nodes, n_edges);
        spmm_kernel<<<n_nodes, 128, 0, stream>>>(x, row_ptr, col, val, out);
        fused_gemm_kernel<<<(n_nodes + 63) / 64, 256, 0, stream>>>(
            x, W_l, b_l, W_r, out, n_nodes);
    }
}